// Round 5
// baseline (325.652 us; speedup 1.0000x reference)
//
#include <hip/hip_runtime.h>
#include <hip/hip_bf16.h>
#include <math.h>

// Problem constants: B=4, T=4096, C=1024, H=16, D=64, BLOCK=128
//   M = B*T = 16384 rows
//   GEMM1: [16384,1024] @ [1024,3072] -> qkv
//   attn : 2048 blocks of (128x64) q,k,v, causal-within-block softmax
//   GEMM2: [16384,1024] @ [1024,1024] + bias -> out (fp32)

typedef __bf16 bf16_t;
typedef __bf16 bf16x8 __attribute__((ext_vector_type(8)));
typedef float  f32x4  __attribute__((ext_vector_type(4)));

typedef const __attribute__((address_space(1))) void* gptr_t;
typedef __attribute__((address_space(3))) void* lptr_t;

// ---------------------------------------------------------------- cvt: f32 -> bf16
__global__ __launch_bounds__(256) void cvt_f32_bf16(const float* __restrict__ in,
                                                    bf16_t* __restrict__ out, size_t n) {
    size_t stride = (size_t)gridDim.x * blockDim.x * 4;
    for (size_t i = ((size_t)blockIdx.x * blockDim.x + threadIdx.x) * 4; i < n; i += stride) {
        float4 v = *(const float4*)(in + i);
        bf16_t t[4];
        t[0] = (bf16_t)v.x; t[1] = (bf16_t)v.y; t[2] = (bf16_t)v.z; t[3] = (bf16_t)v.w;
        *(uint2*)(out + i) = *(uint2*)t;
    }
}

// ------------------------------- transpose+cvt: W[K][N] fp32 -> Wt[N][K] bf16, LDS-tiled
__global__ __launch_bounds__(256) void transpose_cvt(const float* __restrict__ in,
                                                     bf16_t* __restrict__ out, int K, int N) {
    __shared__ float tile[32][33];
    const int tx = threadIdx.x & 31, ty = threadIdx.x >> 5;   // 32 x 8
    const int bx = blockIdx.x, by = blockIdx.y;               // N/32, K/32
    #pragma unroll
    for (int i = 0; i < 4; i++) {
        const int k = by * 32 + ty + i * 8;
        tile[ty + i * 8][tx] = in[(size_t)k * N + bx * 32 + tx];
    }
    __syncthreads();
    #pragma unroll
    for (int i = 0; i < 4; i++) {
        const int n = bx * 32 + ty + i * 8;
        out[(size_t)n * K + by * 32 + tx] = (bf16_t)tile[tx][ty + i * 8];
    }
}

// ---------------------------------------------------------------- GEMM (B-transposed)
// C[M][N] = A[M][K] * Bt[N][K]^T   (bf16 in, fp32 accum)
// ROUND 5: occupancy restructure. 128x256 tile, 8 waves (2Mx4N, each 64x64),
// ring of 3 K=32 slices (A 8KiB + B 16KiB per slot = 72 KiB LDS) -> 2 blocks/CU,
// 16 waves/CU. Cross-block TLP overlaps one block's epilogue/prologue with the
// other's MFMA body (the per-block fixed costs that capped MfmaUtil at ~37%).
// Staging: 3 global_load_lds per wave per slice (1 A + 2 B); stage slice g+2
// during body g; steady vmcnt(3) (tail: 0); ONE barrier per slice with
// lgkmcnt(0) BEFORE it (all waves' ds_reads of slot (g)%3 retired before any
// wave's body-g+1 stage overwrites slot (g+3)%3 == g%3).
// LDS swizzle (rule 21, both sides): 16B chunk ^= (row>>1)&3 on the pre-swizzled
// GLOBAL source (LDS dest linear) and on the ds_read address.
// XCD-chunked swizzle kept: each XCD owns a 16-tile bm strip, bn-outer.
template <bool BF16_OUT, bool BIAS>
__global__ __launch_bounds__(512) void gemm128(const bf16_t* __restrict__ A,
                                               const bf16_t* __restrict__ Bt,
                                               void* __restrict__ Cout,
                                               const float* __restrict__ bias,
                                               int M, int N, int K) {
    // slot layout: [0..4095] A rows 0..127, [4096..12287] B rows 0..255 (k=32 each)
    __shared__ bf16_t ring[3][12288];   // 72 KiB

    const int tid  = threadIdx.x;
    const int lane = tid & 63, wave = tid >> 6;
    const int quad = lane >> 4, l16 = lane & 15;
    const int wm = wave >> 2, wn = wave & 3;   // 2 x 4 wave grid; wave owns 64x64 of C

    // ---- XCD-chunked swizzle over 128-row tiles
    const int nbm  = M >> 7;              // # of bm tiles (128)
    const int mloc = nbm >> 3;            // bm tiles per XCD strip (16)
    const int xcd  = blockIdx.x & 7;
    const int idx  = blockIdx.x >> 3;
    const int bn   = idx / mloc;
    const int bm   = xcd * mloc + (idx - bn * mloc);

    const bf16_t* Ab = A  + (size_t)bm * 128 * K;
    const bf16_t* Bb = Bt + (size_t)bn * 256 * K;

    // staging geometry: one gload = 16 rows x 64B; lane -> (row = l>>2, chunk = l&3)
    const int srow = lane >> 2;
    const int scs  = (lane & 3) ^ ((srow >> 1) & 3);   // pre-swizzled src chunk
    const int rdo  = ((quad ^ ((l16 >> 1) & 3)) << 3); // read-side swizzled elem offset

    f32x4 acc[4][4];
    #pragma unroll
    for (int i = 0; i < 4; ++i)
        #pragma unroll
        for (int j = 0; j < 4; ++j) acc[i][j] = (f32x4){0.f, 0.f, 0.f, 0.f};

    // A: wave stages rows [wave*16, +16)      (8 waves cover 128 rows, 1 gload)
    // B: wave stages rows [wave*32, +32)      (2 gloads)
#define STG(SLICE, SLOT)                                                              \
    do {                                                                              \
        __builtin_amdgcn_global_load_lds(                                             \
            (gptr_t)(Ab + (size_t)(wave * 16 + srow) * K + ((SLICE) << 5) + scs * 8), \
            (lptr_t)&ring[SLOT][wave * 512], 16, 0, 0);                               \
        __builtin_amdgcn_global_load_lds(                                             \
            (gptr_t)(Bb + (size_t)(wave * 32 + srow) * K + ((SLICE) << 5) + scs * 8), \
            (lptr_t)&ring[SLOT][4096 + wave * 1024], 16, 0, 0);                       \
        __builtin_amdgcn_global_load_lds(                                             \
            (gptr_t)(Bb + (size_t)(wave * 32 + 16 + srow) * K + ((SLICE) << 5) +      \
                     scs * 8),                                                        \
            (lptr_t)&ring[SLOT][4096 + wave * 1024 + 512], 16, 0, 0);                 \
    } while (0)

#define BODY(G, RS, SS, DO_STAGE, WAIT_STMT)                                          \
    do {                                                                              \
        const bf16_t* sl_ = ring[RS];                                                 \
        bf16x8 af_[4], bf_[4];                                                        \
        _Pragma("unroll")                                                             \
        for (int fr = 0; fr < 4; ++fr)                                                \
            af_[fr] = *(const bf16x8*)&sl_[(wm * 64 + fr * 16 + l16) * 32 + rdo];     \
        _Pragma("unroll")                                                             \
        for (int fr = 0; fr < 4; ++fr)                                                \
            bf_[fr] =                                                                 \
                *(const bf16x8*)&sl_[4096 + (wn * 64 + fr * 16 + l16) * 32 + rdo];    \
        if (DO_STAGE) STG((G) + 2, SS);                                               \
        asm volatile("s_waitcnt lgkmcnt(0)" ::: "memory");                            \
        WAIT_STMT;                                                                    \
        __builtin_amdgcn_s_barrier();                                                 \
        __builtin_amdgcn_s_setprio(1);                                                \
        _Pragma("unroll")                                                             \
        for (int mr = 0; mr < 4; ++mr)                                                \
            _Pragma("unroll")                                                         \
            for (int nr = 0; nr < 4; ++nr)                                            \
                acc[mr][nr] = __builtin_amdgcn_mfma_f32_16x16x32_bf16(                \
                    af_[mr], bf_[nr], acc[mr][nr], 0, 0, 0);                          \
        __builtin_amdgcn_s_setprio(0);                                                \
    } while (0)

    // prologue: stage slices 0 -> slot0, 1 -> slot1
    STG(0, 0); STG(1, 1);
    asm volatile("s_waitcnt vmcnt(3)" ::: "memory");   // slice 0 landed (1 in flight)
    __builtin_amdgcn_s_barrier();

    const int NS = K >> 5;   // 32 slices
    int rs = 0, ss = 2;
    for (int g = 0; g < NS - 2; ++g) {
        BODY(g, rs, ss, true, asm volatile("s_waitcnt vmcnt(3)" ::: "memory"));
        rs = (rs == 2) ? 0 : rs + 1;
        ss = (ss == 2) ? 0 : ss + 1;
    }
    BODY(NS - 2, rs, ss, false, asm volatile("s_waitcnt vmcnt(0)" ::: "memory"));
    rs = (rs == 2) ? 0 : rs + 1;
    BODY(NS - 1, rs, ss, false, (void)0);
#undef BODY
#undef STG

    // epilogue: C/D layout col=lane&15, row=quad*4+reg
    #pragma unroll
    for (int mr = 0; mr < 4; ++mr) {
        #pragma unroll
        for (int nr = 0; nr < 4; ++nr) {
            const int gcol = bn * 256 + wn * 64 + nr * 16 + l16;
            #pragma unroll
            for (int reg = 0; reg < 4; ++reg) {
                const int grow = bm * 128 + wm * 64 + mr * 16 + quad * 4 + reg;
                float v = acc[mr][nr][reg];
                if (BIAS) v += bias[gcol];
                if (BF16_OUT)
                    ((bf16_t*)Cout)[(size_t)grow * N + gcol] = (bf16_t)v;
                else
                    ((float*)Cout)[(size_t)grow * N + gcol] = v;
            }
        }
    }
}

// ---------------------------------------------------------------- block-local attention
// One workgroup per (b, blk, h). q,k: [128][72] LDS; v stored TRANSPOSED [64][136] so
// PV B-fragments are ds_read_b128. LDS total 54272 B -> 3 blocks/CU.
__global__ __launch_bounds__(256, 3) void attn_kernel(const bf16_t* __restrict__ qkv,
                                                      bf16_t* __restrict__ attn_out) {
    __shared__ __align__(16) char smem[54272];
    bf16_t* qs = (bf16_t*)smem;                   // [128][72]
    bf16_t* ks = (bf16_t*)(smem + 18432);         // [128][72]
    bf16_t* vT = (bf16_t*)(smem + 36864);         // [64][136]  vT[c][r] = v[r][c]
    bf16_t* ps = (bf16_t*)smem;                   // [128][136] overlays qs+ks (34816 <= 36864)

    const int tid = threadIdx.x;
    const int lane = tid & 63, wave = tid >> 6;
    const int quad = lane >> 4, l16 = lane & 15;

    const int bid = blockIdx.x;
    const int h = bid & 15;
    const int blk = (bid >> 4) & 31;
    const int b = bid >> 9;
    const int row0 = (b * 32 + blk) * 128;   // row base in [16384]
    const int LDQ = 3072;

    // ---- stage q,k (vector), v transposed (scalar scatter, one-time)
    for (int t = tid; t < 128 * 8; t += 256) {
        const int r = t >> 3;
        const int c = (t & 7) * 8;           // element offset
        const bf16_t* src = qkv + (size_t)(row0 + r) * LDQ + h * 64;
        *(uint4*)&qs[r * 72 + c] = *(const uint4*)(src + c);
        *(uint4*)&ks[r * 72 + c] = *(const uint4*)(src + 1024 + c);
        bf16x8 vv = *(const bf16x8*)(src + 2048 + c);
        #pragma unroll
        for (int j = 0; j < 8; j++)
            vT[(c + j) * 136 + r] = vv[j];
    }
    __syncthreads();

    // ---- S = q k^T / 8 : wave handles rows [wave*32, wave*32+32) x 128 cols
    f32x4 sfrag[2][8];
    for (int mr = 0; mr < 2; mr++)
        for (int nc = 0; nc < 8; nc++)
            sfrag[mr][nc] = (f32x4){0.f, 0.f, 0.f, 0.f};

    #pragma unroll
    for (int ksl = 0; ksl < 2; ksl++) {     // K=64 in two slices of 32
        bf16x8 aq[2], bk[8];
        #pragma unroll
        for (int mr = 0; mr < 2; mr++)
            aq[mr] = *(const bf16x8*)&qs[(wave * 32 + mr * 16 + l16) * 72 + ksl * 32 + quad * 8];
        #pragma unroll
        for (int nc = 0; nc < 8; nc++)
            bk[nc] = *(const bf16x8*)&ks[(nc * 16 + l16) * 72 + ksl * 32 + quad * 8];
        #pragma unroll
        for (int mr = 0; mr < 2; mr++)
            #pragma unroll
            for (int nc = 0; nc < 8; nc++)
                sfrag[mr][nc] = __builtin_amdgcn_mfma_f32_16x16x32_bf16(aq[mr], bk[nc], sfrag[mr][nc], 0, 0, 0);
    }

    // ---- scale + causal mask (C-layout: row=quad*4+reg, col=nc*16+l16)
    #pragma unroll
    for (int mr = 0; mr < 2; mr++) {
        #pragma unroll
        for (int nc = 0; nc < 8; nc++) {
            #pragma unroll
            for (int reg = 0; reg < 4; reg++) {
                const int row = wave * 32 + mr * 16 + quad * 4 + reg;
                const int col = nc * 16 + l16;
                float s = sfrag[mr][nc][reg] * 0.125f;
                if (col > row) s = -INFINITY;
                sfrag[mr][nc][reg] = s;
            }
        }
    }

    // ---- softmax per row (reduce across 16 lanes of the row-group + 8 col frags)
    #pragma unroll
    for (int mr = 0; mr < 2; mr++) {
        #pragma unroll
        for (int reg = 0; reg < 4; reg++) {
            float m = -INFINITY;
            #pragma unroll
            for (int nc = 0; nc < 8; nc++) m = fmaxf(m, sfrag[mr][nc][reg]);
            #pragma unroll
            for (int off = 1; off < 16; off <<= 1) m = fmaxf(m, __shfl_xor(m, off));
            float sum = 0.f;
            #pragma unroll
            for (int nc = 0; nc < 8; nc++) {
                float e = __expf(sfrag[mr][nc][reg] - m);
                sfrag[mr][nc][reg] = e;
                sum += e;
            }
            #pragma unroll
            for (int off = 1; off < 16; off <<= 1) sum += __shfl_xor(sum, off);
            const float inv = 1.0f / (sum + 1e-6f);
            #pragma unroll
            for (int nc = 0; nc < 8; nc++) sfrag[mr][nc][reg] *= inv;
        }
    }

    __syncthreads();   // all waves done reading qs/ks before P overlays them

    // ---- write P (bf16) to LDS [128][136]
    #pragma unroll
    for (int mr = 0; mr < 2; mr++)
        #pragma unroll
        for (int nc = 0; nc < 8; nc++)
            #pragma unroll
            for (int reg = 0; reg < 4; reg++) {
                const int row = wave * 32 + mr * 16 + quad * 4 + reg;
                const int col = nc * 16 + l16;
                ps[row * 136 + col] = (bf16_t)sfrag[mr][nc][reg];
            }
    __syncthreads();

    // ---- O = P @ V : rows [wave*32, +32) x 64 cols, K=128 in 4 slices; V from vT (b128)
    f32x4 oacc[2][4];
    for (int mr = 0; mr < 2; mr++)
        for (int nd = 0; nd < 4; nd++)
            oacc[mr][nd] = (f32x4){0.f, 0.f, 0.f, 0.f};

    #pragma unroll
    for (int ksl = 0; ksl < 4; ksl++) {
        bf16x8 ap[2];
        #pragma unroll
        for (int mr = 0; mr < 2; mr++)
            ap[mr] = *(const bf16x8*)&ps[(wave * 32 + mr * 16 + l16) * 136 + ksl * 32 + quad * 8];
        #pragma unroll
        for (int nd = 0; nd < 4; nd++) {
            bf16x8 bv = *(const bf16x8*)&vT[(nd * 16 + l16) * 136 + ksl * 32 + quad * 8];
            #pragma unroll
            for (int mr = 0; mr < 2; mr++)
                oacc[mr][nd] = __builtin_amdgcn_mfma_f32_16x16x32_bf16(ap[mr], bv, oacc[mr][nd], 0, 0, 0);
        }
    }

    // ---- store O bf16 into attn buffer [16384][1024]
    #pragma unroll
    for (int mr = 0; mr < 2; mr++)
        #pragma unroll
        for (int nd = 0; nd < 4; nd++)
            #pragma unroll
            for (int reg = 0; reg < 4; reg++) {
                const int row = row0 + wave * 32 + mr * 16 + quad * 4 + reg;
                const int col = h * 64 + nd * 16 + l16;
                attn_out[(size_t)row * 1024 + col] = (bf16_t)oacc[mr][nd][reg];
            }
}

// ---------------------------------------------------------------- launch
extern "C" void kernel_launch(void* const* d_in, const int* in_sizes, int n_in,
                              void* d_out, int out_size, void* d_ws, size_t ws_size,
                              hipStream_t stream) {
    const float* x     = (const float*)d_in[0];   // [4,4096,1024]
    const float* Wqkv  = (const float*)d_in[1];   // [1024,3072]
    const float* Wproj = (const float*)d_in[2];   // [1024,1024]
    const float* bproj = (const float*)d_in[3];   // [1024]

    const int M = 16384, C = 1024, N1 = 3072;

    // workspace carve (bytes): all 16B aligned
    char* ws = (char*)d_ws;
    bf16_t* xb     = (bf16_t*)(ws);                                   // 32 MB
    bf16_t* wqkvT  = (bf16_t*)(ws + 33554432);                        //  6 MB  [3072][1024]
    bf16_t* wprojT = (bf16_t*)(ws + 39845888);                        //  2 MB  [1024][1024]
    bf16_t* qkvb   = (bf16_t*)(ws + 41943040);                        // 96 MB  [16384][3072]
    bf16_t* attnb  = (bf16_t*)(ws + 142606336);                       // 32 MB  [16384][1024]
    // total 168 MB

    cvt_f32_bf16<<<8192, 256, 0, stream>>>(x, xb, (size_t)M * C);
    transpose_cvt<<<dim3(N1 / 32, C / 32), 256, 0, stream>>>(Wqkv, wqkvT, C, N1);
    transpose_cvt<<<dim3(C / 32, C / 32), 256, 0, stream>>>(Wproj, wprojT, C, C);

    // 1D grids, XCD-chunk-swizzled in-kernel: GEMM1 1536 = 8*192, GEMM2 512 = 8*64
    gemm128<true, false><<<(N1 / 256) * (M / 128), 512, 0, stream>>>(
        xb, wqkvT, (void*)qkvb, nullptr, M, N1, C);

    attn_kernel<<<2048, 256, 0, stream>>>(qkvb, attnb);

    gemm128<false, true><<<(C / 256) * (M / 128), 512, 0, stream>>>(
        attnb, wprojT, d_out, bproj, M, C, C);
}

// Round 6
// 315.164 us; speedup vs baseline: 1.0333x; 1.0333x over previous
//
#include <hip/hip_runtime.h>
#include <hip/hip_bf16.h>
#include <math.h>

// Problem constants: B=4, T=4096, C=1024, H=16, D=64, BLOCK=128
//   M = B*T = 16384 rows
//   GEMM1: [16384,1024] @ [1024,3072] -> qkv
//   attn : 2048 blocks of (128x64) q,k,v, causal-within-block softmax
//   GEMM2: [16384,1024] @ [1024,1024] + bias -> out (fp32)

typedef __bf16 bf16_t;
typedef __bf16 bf16x8 __attribute__((ext_vector_type(8)));
typedef float  f32x4  __attribute__((ext_vector_type(4)));

typedef const __attribute__((address_space(1))) void* gptr_t;
typedef __attribute__((address_space(3))) void* lptr_t;

// ---------------------------------------------------------------- fused prepass
// One dispatch: cvt x->xb (blocks 0..8191), transpose Wqkv (8192..11263),
// transpose Wproj (11264..12287). All memory-bound + independent; fusing them
// overlaps the three passes and removes two serial launch drains.
__global__ __launch_bounds__(256) void prepass(const float* __restrict__ x,
                                               bf16_t* __restrict__ xb,
                                               const float* __restrict__ Wqkv,
                                               bf16_t* __restrict__ wqkvT,
                                               const float* __restrict__ Wproj,
                                               bf16_t* __restrict__ wprojT) {
    __shared__ float tile[32][33];
    const int bid = blockIdx.x;
    if (bid < 8192) {
        // ---- cvt f32 -> bf16, virtual grid 8192
        const size_t n = (size_t)16384 * 1024;
        const size_t stride = (size_t)8192 * 256 * 4;
        for (size_t i = ((size_t)bid * 256 + threadIdx.x) * 4; i < n; i += stride) {
            float4 v = *(const float4*)(x + i);
            bf16_t t[4];
            t[0] = (bf16_t)v.x; t[1] = (bf16_t)v.y; t[2] = (bf16_t)v.z; t[3] = (bf16_t)v.w;
            *(uint2*)(xb + i) = *(uint2*)t;
        }
        return;
    }
    // ---- transpose+cvt W[K][N] -> Wt[N][K]
    const float* in;
    bf16_t* out;
    int K, N, bx, by;
    if (bid < 8192 + 3072) {
        const int t = bid - 8192;
        in = Wqkv; out = wqkvT; K = 1024; N = 3072;
        bx = t % 96; by = t / 96;
    } else {
        const int t = bid - 11264;
        in = Wproj; out = wprojT; K = 1024; N = 1024;
        bx = t & 31; by = t >> 5;
    }
    const int tx = threadIdx.x & 31, ty = threadIdx.x >> 5;   // 32 x 8
    #pragma unroll
    for (int i = 0; i < 4; i++) {
        const int k = by * 32 + ty + i * 8;
        tile[ty + i * 8][tx] = in[(size_t)k * N + bx * 32 + tx];
    }
    __syncthreads();
    #pragma unroll
    for (int i = 0; i < 4; i++) {
        const int n = bx * 32 + ty + i * 8;
        out[(size_t)n * K + by * 32 + tx] = (bf16_t)tile[tx][ty + i * 8];
    }
}

// ---------------------------------------------------------------- GEMM (B-transposed)
// C[M][N] = A[M][K] * Bt[N][K]^T   (bf16 in, fp32 accum)
// ROUND 6: 256x128 tile, 4 waves (2Mx2N), wave-tile 128x64 -> acc 8x4.
// Rationale: round-5's 4x4 acc reads 8 ds_read_b128 per 16 MFMA (0.5/MFMA) ->
// LDS-read port co-critical with MFMA, capping MfmaUtil ~40%. 8x4 acc reads
// 12 per 32 MFMA (0.375/MFMA, the m201 template's ratio) AND keeps 2 blocks/CU
// (ring of 3 K=32 slots: A 16KiB + B 8KiB = 24KiB/slot, 72 KiB total).
// Staging: 6 global_load_lds per wave per slice (4 A + 2 B); stage slice g+2
// during body g; steady vmcnt(6) = "slice g+1 landed, 6 in flight" (guarantees
// body g+1's early ds_reads); drains only in the 2-body tail. One barrier per
// slice, lgkmcnt(0) before it (WAR protection for the restaged slot).
// LDS swizzle (rule 21, both sides): 16B chunk ^= (row>>1)&3 on the pre-swizzled
// GLOBAL source (LDS dest linear) and on the ds_read address.
// XCD-chunked swizzle: each XCD owns an 8-tile bm strip, bn-outer.
template <bool BF16_OUT, bool BIAS>
__global__ __launch_bounds__(256, 2) void gemm256x128(const bf16_t* __restrict__ A,
                                                      const bf16_t* __restrict__ Bt,
                                                      void* __restrict__ Cout,
                                                      const float* __restrict__ bias,
                                                      int M, int N, int K) {
    // slot layout: [0..8191] A rows 0..255, [8192..12287] B rows 0..127 (k=32 each)
    __shared__ bf16_t ring[3][12288];   // 72 KiB

    const int tid  = threadIdx.x;
    const int lane = tid & 63, wave = tid >> 6;          // 4 waves
    const int quad = lane >> 4, l16 = lane & 15;
    const int wm = wave >> 1, wn = wave & 1;             // 2x2; wave owns 128x64 of C

    // ---- XCD-chunked swizzle over 256-row tiles
    const int nbm  = M >> 8;              // # of bm tiles (64)
    const int mloc = nbm >> 3;            // bm tiles per XCD strip (8)
    const int xcd  = blockIdx.x & 7;
    const int idx  = blockIdx.x >> 3;
    const int bn   = idx / mloc;
    const int bm   = xcd * mloc + (idx - bn * mloc);

    const bf16_t* Ab = A  + (size_t)bm * 256 * K;
    const bf16_t* Bb = Bt + (size_t)bn * 128 * K;

    // staging geometry: one gload = 16 rows x 64B; lane -> (row = l>>2, chunk = l&3)
    const int srow = lane >> 2;
    const int scs  = (lane & 3) ^ ((srow >> 1) & 3);   // pre-swizzled src chunk
    const int rdo  = ((quad ^ ((l16 >> 1) & 3)) << 3); // read-side swizzled elem offset

    f32x4 acc[8][4];
    #pragma unroll
    for (int i = 0; i < 8; ++i)
        #pragma unroll
        for (int j = 0; j < 4; ++j) acc[i][j] = (f32x4){0.f, 0.f, 0.f, 0.f};

    // A: wave stages rows [wave*64, +64) (4 gloads); B: rows [wave*32, +32) (2 gloads)
#define STG(SLICE, SLOT)                                                              \
    do {                                                                              \
        _Pragma("unroll")                                                             \
        for (int i_ = 0; i_ < 4; ++i_)                                                \
            __builtin_amdgcn_global_load_lds(                                         \
                (gptr_t)(Ab + (size_t)(wave * 64 + i_ * 16 + srow) * K +              \
                         ((SLICE) << 5) + scs * 8),                                   \
                (lptr_t)&ring[SLOT][(wave * 64 + i_ * 16) * 32], 16, 0, 0);           \
        _Pragma("unroll")                                                             \
        for (int i_ = 0; i_ < 2; ++i_)                                                \
            __builtin_amdgcn_global_load_lds(                                         \
                (gptr_t)(Bb + (size_t)(wave * 32 + i_ * 16 + srow) * K +              \
                         ((SLICE) << 5) + scs * 8),                                   \
                (lptr_t)&ring[SLOT][8192 + (wave * 32 + i_ * 16) * 32], 16, 0, 0);    \
    } while (0)

#define BODY(G, RS, SS, DO_STAGE, WAIT_STMT)                                          \
    do {                                                                              \
        const bf16_t* sl_ = ring[RS];                                                 \
        bf16x8 af_[8], bf_[4];                                                        \
        _Pragma("unroll")                                                             \
        for (int fr = 0; fr < 8; ++fr)                                                \
            af_[fr] = *(const bf16x8*)&sl_[(wm * 128 + fr * 16 + l16) * 32 + rdo];    \
        _Pragma("unroll")                                                             \
        for (int fr = 0; fr < 4; ++fr)                                                \
            bf_[fr] =                                                                 \
                *(const bf16x8*)&sl_[8192 + (wn * 64 + fr * 16 + l16) * 32 + rdo];    \
        if (DO_STAGE) STG((G) + 2, SS);                                               \
        asm volatile("s_waitcnt lgkmcnt(0)" ::: "memory");                            \
        WAIT_STMT;                                                                    \
        __builtin_amdgcn_s_barrier();                                                 \
        __builtin_amdgcn_s_setprio(1);                                                \
        _Pragma("unroll")                                                             \
        for (int mr = 0; mr < 8; ++mr)                                                \
            _Pragma("unroll")                                                         \
            for (int nr = 0; nr < 4; ++nr)                                            \
                acc[mr][nr] = __builtin_amdgcn_mfma_f32_16x16x32_bf16(                \
                    af_[mr], bf_[nr], acc[mr][nr], 0, 0, 0);                          \
        __builtin_amdgcn_s_setprio(0);                                                \
    } while (0)

    // prologue: stage slices 0 -> slot0, 1 -> slot1 (12 loads in flight)
    STG(0, 0); STG(1, 1);
    asm volatile("s_waitcnt vmcnt(6)" ::: "memory");   // slice 0 landed (6 in flight)
    __builtin_amdgcn_s_barrier();

    const int NS = K >> 5;   // 32 slices
    int rs = 0, ss = 2;
    for (int g = 0; g < NS - 2; ++g) {
        BODY(g, rs, ss, true, asm volatile("s_waitcnt vmcnt(6)" ::: "memory"));
        rs = (rs == 2) ? 0 : rs + 1;
        ss = (ss == 2) ? 0 : ss + 1;
    }
    BODY(NS - 2, rs, ss, false, asm volatile("s_waitcnt vmcnt(0)" ::: "memory"));
    rs = (rs == 2) ? 0 : rs + 1;
    BODY(NS - 1, rs, ss, false, (void)0);
#undef BODY
#undef STG

    // epilogue: C/D layout col=lane&15, row=quad*4+reg
    #pragma unroll
    for (int mr = 0; mr < 8; ++mr) {
        #pragma unroll
        for (int nr = 0; nr < 4; ++nr) {
            const int gcol = bn * 128 + wn * 64 + nr * 16 + l16;
            #pragma unroll
            for (int reg = 0; reg < 4; ++reg) {
                const int grow = bm * 256 + wm * 128 + mr * 16 + quad * 4 + reg;
                float v = acc[mr][nr][reg];
                if (BIAS) v += bias[gcol];
                if (BF16_OUT)
                    ((bf16_t*)Cout)[(size_t)grow * N + gcol] = (bf16_t)v;
                else
                    ((float*)Cout)[(size_t)grow * N + gcol] = v;
            }
        }
    }
}

// ---------------------------------------------------------------- block-local attention
// One workgroup per (b, blk, h). q,k: [128][72] LDS; v stored TRANSPOSED [64][136] so
// PV B-fragments are ds_read_b128. LDS total 54272 B -> 3 blocks/CU.
__global__ __launch_bounds__(256, 3) void attn_kernel(const bf16_t* __restrict__ qkv,
                                                      bf16_t* __restrict__ attn_out) {
    __shared__ __align__(16) char smem[54272];
    bf16_t* qs = (bf16_t*)smem;                   // [128][72]
    bf16_t* ks = (bf16_t*)(smem + 18432);         // [128][72]
    bf16_t* vT = (bf16_t*)(smem + 36864);         // [64][136]  vT[c][r] = v[r][c]
    bf16_t* ps = (bf16_t*)smem;                   // [128][136] overlays qs+ks (34816 <= 36864)

    const int tid = threadIdx.x;
    const int lane = tid & 63, wave = tid >> 6;
    const int quad = lane >> 4, l16 = lane & 15;

    const int bid = blockIdx.x;
    const int h = bid & 15;
    const int blk = (bid >> 4) & 31;
    const int b = bid >> 9;
    const int row0 = (b * 32 + blk) * 128;   // row base in [16384]
    const int LDQ = 3072;

    // ---- stage q,k (vector), v transposed (scalar scatter, one-time)
    for (int t = tid; t < 128 * 8; t += 256) {
        const int r = t >> 3;
        const int c = (t & 7) * 8;           // element offset
        const bf16_t* src = qkv + (size_t)(row0 + r) * LDQ + h * 64;
        *(uint4*)&qs[r * 72 + c] = *(const uint4*)(src + c);
        *(uint4*)&ks[r * 72 + c] = *(const uint4*)(src + 1024 + c);
        bf16x8 vv = *(const bf16x8*)(src + 2048 + c);
        #pragma unroll
        for (int j = 0; j < 8; j++)
            vT[(c + j) * 136 + r] = vv[j];
    }
    __syncthreads();

    // ---- S = q k^T / 8 : wave handles rows [wave*32, wave*32+32) x 128 cols
    f32x4 sfrag[2][8];
    for (int mr = 0; mr < 2; mr++)
        for (int nc = 0; nc < 8; nc++)
            sfrag[mr][nc] = (f32x4){0.f, 0.f, 0.f, 0.f};

    #pragma unroll
    for (int ksl = 0; ksl < 2; ksl++) {     // K=64 in two slices of 32
        bf16x8 aq[2], bk[8];
        #pragma unroll
        for (int mr = 0; mr < 2; mr++)
            aq[mr] = *(const bf16x8*)&qs[(wave * 32 + mr * 16 + l16) * 72 + ksl * 32 + quad * 8];
        #pragma unroll
        for (int nc = 0; nc < 8; nc++)
            bk[nc] = *(const bf16x8*)&ks[(nc * 16 + l16) * 72 + ksl * 32 + quad * 8];
        #pragma unroll
        for (int mr = 0; mr < 2; mr++)
            #pragma unroll
            for (int nc = 0; nc < 8; nc++)
                sfrag[mr][nc] = __builtin_amdgcn_mfma_f32_16x16x32_bf16(aq[mr], bk[nc], sfrag[mr][nc], 0, 0, 0);
    }

    // ---- scale + causal mask (C-layout: row=quad*4+reg, col=nc*16+l16)
    #pragma unroll
    for (int mr = 0; mr < 2; mr++) {
        #pragma unroll
        for (int nc = 0; nc < 8; nc++) {
            #pragma unroll
            for (int reg = 0; reg < 4; reg++) {
                const int row = wave * 32 + mr * 16 + quad * 4 + reg;
                const int col = nc * 16 + l16;
                float s = sfrag[mr][nc][reg] * 0.125f;
                if (col > row) s = -INFINITY;
                sfrag[mr][nc][reg] = s;
            }
        }
    }

    // ---- softmax per row (reduce across 16 lanes of the row-group + 8 col frags)
    #pragma unroll
    for (int mr = 0; mr < 2; mr++) {
        #pragma unroll
        for (int reg = 0; reg < 4; reg++) {
            float m = -INFINITY;
            #pragma unroll
            for (int nc = 0; nc < 8; nc++) m = fmaxf(m, sfrag[mr][nc][reg]);
            #pragma unroll
            for (int off = 1; off < 16; off <<= 1) m = fmaxf(m, __shfl_xor(m, off));
            float sum = 0.f;
            #pragma unroll
            for (int nc = 0; nc < 8; nc++) {
                float e = __expf(sfrag[mr][nc][reg] - m);
                sfrag[mr][nc][reg] = e;
                sum += e;
            }
            #pragma unroll
            for (int off = 1; off < 16; off <<= 1) sum += __shfl_xor(sum, off);
            const float inv = 1.0f / (sum + 1e-6f);
            #pragma unroll
            for (int nc = 0; nc < 8; nc++) sfrag[mr][nc][reg] *= inv;
        }
    }

    __syncthreads();   // all waves done reading qs/ks before P overlays them

    // ---- write P (bf16) to LDS [128][136]
    #pragma unroll
    for (int mr = 0; mr < 2; mr++)
        #pragma unroll
        for (int nc = 0; nc < 8; nc++)
            #pragma unroll
            for (int reg = 0; reg < 4; reg++) {
                const int row = wave * 32 + mr * 16 + quad * 4 + reg;
                const int col = nc * 16 + l16;
                ps[row * 136 + col] = (bf16_t)sfrag[mr][nc][reg];
            }
    __syncthreads();

    // ---- O = P @ V : rows [wave*32, +32) x 64 cols, K=128 in 4 slices; V from vT (b128)
    f32x4 oacc[2][4];
    for (int mr = 0; mr < 2; mr++)
        for (int nd = 0; nd < 4; nd++)
            oacc[mr][nd] = (f32x4){0.f, 0.f, 0.f, 0.f};

    #pragma unroll
    for (int ksl = 0; ksl < 4; ksl++) {
        bf16x8 ap[2];
        #pragma unroll
        for (int mr = 0; mr < 2; mr++)
            ap[mr] = *(const bf16x8*)&ps[(wave * 32 + mr * 16 + l16) * 136 + ksl * 32 + quad * 8];
        #pragma unroll
        for (int nd = 0; nd < 4; nd++) {
            bf16x8 bv = *(const bf16x8*)&vT[(nd * 16 + l16) * 136 + ksl * 32 + quad * 8];
            #pragma unroll
            for (int mr = 0; mr < 2; mr++)
                oacc[mr][nd] = __builtin_amdgcn_mfma_f32_16x16x32_bf16(ap[mr], bv, oacc[mr][nd], 0, 0, 0);
        }
    }

    // ---- store O bf16 into attn buffer [16384][1024]
    #pragma unroll
    for (int mr = 0; mr < 2; mr++)
        #pragma unroll
        for (int nd = 0; nd < 4; nd++)
            #pragma unroll
            for (int reg = 0; reg < 4; reg++) {
                const int row = row0 + wave * 32 + mr * 16 + quad * 4 + reg;
                const int col = h * 64 + nd * 16 + l16;
                attn_out[(size_t)row * 1024 + col] = (bf16_t)oacc[mr][nd][reg];
            }
}

// ---------------------------------------------------------------- launch
extern "C" void kernel_launch(void* const* d_in, const int* in_sizes, int n_in,
                              void* d_out, int out_size, void* d_ws, size_t ws_size,
                              hipStream_t stream) {
    const float* x     = (const float*)d_in[0];   // [4,4096,1024]
    const float* Wqkv  = (const float*)d_in[1];   // [1024,3072]
    const float* Wproj = (const float*)d_in[2];   // [1024,1024]
    const float* bproj = (const float*)d_in[3];   // [1024]

    const int M = 16384, C = 1024, N1 = 3072;

    // workspace carve (bytes): all 16B aligned
    char* ws = (char*)d_ws;
    bf16_t* xb     = (bf16_t*)(ws);                                   // 32 MB
    bf16_t* wqkvT  = (bf16_t*)(ws + 33554432);                        //  6 MB  [3072][1024]
    bf16_t* wprojT = (bf16_t*)(ws + 39845888);                        //  2 MB  [1024][1024]
    bf16_t* qkvb   = (bf16_t*)(ws + 41943040);                        // 96 MB  [16384][3072]
    bf16_t* attnb  = (bf16_t*)(ws + 142606336);                       // 32 MB  [16384][1024]
    // total 168 MB

    prepass<<<12288, 256, 0, stream>>>(x, xb, Wqkv, wqkvT, Wproj, wprojT);

    // 1D grids, XCD-chunk-swizzled in-kernel: GEMM1 1536 = 8*192, GEMM2 512 = 8*64
    gemm256x128<true, false><<<(N1 / 128) * (M / 256), 256, 0, stream>>>(
        xb, wqkvT, (void*)qkvb, nullptr, M, N1, C);

    attn_kernel<<<2048, 256, 0, stream>>>(qkvb, attnb);

    gemm256x128<false, true><<<(C / 128) * (M / 256), 256, 0, stream>>>(
        attnb, wprojT, d_out, bproj, M, C, C);
}

// Round 7
// 300.871 us; speedup vs baseline: 1.0824x; 1.0475x over previous
//
#include <hip/hip_runtime.h>
#include <hip/hip_bf16.h>
#include <math.h>

// Problem constants: B=4, T=4096, C=1024, H=16, D=64, BLOCK=128
//   M = B*T = 16384 rows
//   GEMM1: [16384,1024] @ [1024,3072] -> qkv
//   attn : 2048 blocks of (128x64) q,k,v, causal-within-block softmax
//   GEMM2: [16384,1024] @ [1024,1024] + bias -> out (fp32)

typedef __bf16 bf16_t;
typedef __bf16 bf16x8 __attribute__((ext_vector_type(8)));
typedef unsigned short u16x8 __attribute__((ext_vector_type(8)));
typedef float  f32x4  __attribute__((ext_vector_type(4)));

typedef const __attribute__((address_space(1))) void* gptr_t;
typedef __attribute__((address_space(3))) void* lptr_t;

// ---------------------------------------------------------------- fused prepass
__global__ __launch_bounds__(256) void prepass(const float* __restrict__ x,
                                               bf16_t* __restrict__ xb,
                                               const float* __restrict__ Wqkv,
                                               bf16_t* __restrict__ wqkvT,
                                               const float* __restrict__ Wproj,
                                               bf16_t* __restrict__ wprojT) {
    __shared__ float tile[32][33];
    const int bid = blockIdx.x;
    if (bid < 8192) {
        const size_t n = (size_t)16384 * 1024;
        const size_t stride = (size_t)8192 * 256 * 4;
        for (size_t i = ((size_t)bid * 256 + threadIdx.x) * 4; i < n; i += stride) {
            float4 v = *(const float4*)(x + i);
            bf16_t t[4];
            t[0] = (bf16_t)v.x; t[1] = (bf16_t)v.y; t[2] = (bf16_t)v.z; t[3] = (bf16_t)v.w;
            *(uint2*)(xb + i) = *(uint2*)t;
        }
        return;
    }
    const float* in;
    bf16_t* out;
    int K, N, bx, by;
    if (bid < 8192 + 3072) {
        const int t = bid - 8192;
        in = Wqkv; out = wqkvT; K = 1024; N = 3072;
        bx = t % 96; by = t / 96;
    } else {
        const int t = bid - 11264;
        in = Wproj; out = wprojT; K = 1024; N = 1024;
        bx = t & 31; by = t >> 5;
    }
    const int tx = threadIdx.x & 31, ty = threadIdx.x >> 5;   // 32 x 8
    #pragma unroll
    for (int i = 0; i < 4; i++) {
        const int k = by * 32 + ty + i * 8;
        tile[ty + i * 8][tx] = in[(size_t)k * N + bx * 32 + tx];
    }
    __syncthreads();
    #pragma unroll
    for (int i = 0; i < 4; i++) {
        const int n = bx * 32 + ty + i * 8;
        out[(size_t)n * K + by * 32 + tx] = (bf16_t)tile[tx][ty + i * 8];
    }
}

// ---------------------------------------------------------------- GEMM (B-transposed)
// C[M][N] = A[M][K] * Bt[N][K]^T   (bf16 in, fp32 accum)
// ROUND 7: test the staging-delivery-ceiling hypothesis (~20 B/cy/CU via
// global_load_lds). 256x256 tile stages 7.6 B/KFLOP (vs 11.4 for the 128-wide
// tiles that all plateaued at ~940 TF = 87% of the 11.4-implied bound; m201's
// 256^2 = 1563 TF sits exactly AT the 7.6-implied bound). To keep TLP (the r3
// failure was 1 block/CU lockstep), use 16 waves of 64 threads (1024 thr):
// wave-tile 64x64 -> acc 4x4 f32x4 = 64 VGPR, total ~115 -> <=128 VGPR class
// -> all 16 waves resident (4/SIMD). __launch_bounds__(1024,4) enforces it.
// Ring of 3 K=32 slices (A 16KB + B 16KB per slot) = 96 KB LDS.
// Per body g: 8 swizzled ds_read_b128 (af4,bf4); stage slot g+2 (2 gloads/wave);
// vmcnt(2) [counted: g+1's 2 loads stay in flight; 0 only in 2-body tail];
// barrier; setprio(1) 16 MFMA setprio(0). Both-sides chunk-XOR swizzle as r6
// (measured 0 conflicts). XCD-chunked bm strips kept.
template <bool BF16_OUT, bool BIAS>
__global__ __launch_bounds__(1024, 4) void gemm256q(const bf16_t* __restrict__ A,
                                                    const bf16_t* __restrict__ Bt,
                                                    void* __restrict__ Cout,
                                                    const float* __restrict__ bias,
                                                    int M, int N, int K) {
    // slot: elems [0..8191] = A rows 0..255 (32 elem each), [8192..16383] = B rows
    __shared__ bf16_t ring[3][16384];   // 96 KiB

    const int tid  = threadIdx.x;
    const int lane = tid & 63, wave = tid >> 6;          // 16 waves
    const int quad = lane >> 4, l16 = lane & 15;
    const int wm = wave >> 2, wn = wave & 3;             // 4x4; wave owns 64x64 of C

    // ---- XCD-chunked swizzle over 256-row tiles
    const int nbm  = M >> 8;              // 64
    const int mloc = nbm >> 3;            // 8 per XCD strip
    const int xcd  = blockIdx.x & 7;
    const int idx  = blockIdx.x >> 3;
    const int bn   = idx / mloc;
    const int bm   = xcd * mloc + (idx - bn * mloc);

    const bf16_t* Ab = A  + (size_t)bm * 256 * K;
    const bf16_t* Bb = Bt + (size_t)bn * 256 * K;

    // staging: one gload = 16 rows x 64B; lane -> (row = lane>>2, chunk = lane&3)
    const int srow = lane >> 2;
    const int scs  = (lane & 3) ^ ((srow >> 1) & 3);   // pre-swizzled src chunk
    const int rdo  = ((quad ^ ((l16 >> 1) & 3)) << 3); // read-side swizzled elem off

    f32x4 acc[4][4];
    #pragma unroll
    for (int i = 0; i < 4; ++i)
        #pragma unroll
        for (int j = 0; j < 4; ++j) acc[i][j] = (f32x4){0.f, 0.f, 0.f, 0.f};

    // A: wave stages rows [wave*16,+16) (1 gload); B: same rows of Bt (1 gload)
#define STG(SLICE, SLOT)                                                              \
    do {                                                                              \
        __builtin_amdgcn_global_load_lds(                                             \
            (gptr_t)(Ab + (size_t)(wave * 16 + srow) * K + ((SLICE) << 5) + scs * 8), \
            (lptr_t)&ring[SLOT][wave * 512], 16, 0, 0);                               \
        __builtin_amdgcn_global_load_lds(                                             \
            (gptr_t)(Bb + (size_t)(wave * 16 + srow) * K + ((SLICE) << 5) + scs * 8), \
            (lptr_t)&ring[SLOT][8192 + wave * 512], 16, 0, 0);                        \
    } while (0)

#define BODY(G, RS, SS, DO_STAGE, WAIT_STMT)                                          \
    do {                                                                              \
        const bf16_t* sl_ = ring[RS];                                                 \
        bf16x8 af_[4], bf_[4];                                                        \
        _Pragma("unroll")                                                             \
        for (int fr = 0; fr < 4; ++fr)                                                \
            af_[fr] = *(const bf16x8*)&sl_[(wm * 64 + fr * 16 + l16) * 32 + rdo];     \
        _Pragma("unroll")                                                             \
        for (int fr = 0; fr < 4; ++fr)                                                \
            bf_[fr] =                                                                 \
                *(const bf16x8*)&sl_[8192 + (wn * 64 + fr * 16 + l16) * 32 + rdo];    \
        if (DO_STAGE) STG((G) + 2, SS);                                               \
        WAIT_STMT;                                                                    \
        __builtin_amdgcn_s_barrier();                                                 \
        __builtin_amdgcn_s_setprio(1);                                                \
        _Pragma("unroll")                                                             \
        for (int mr = 0; mr < 4; ++mr)                                                \
            _Pragma("unroll")                                                         \
            for (int nr = 0; nr < 4; ++nr)                                            \
                acc[mr][nr] = __builtin_amdgcn_mfma_f32_16x16x32_bf16(                \
                    af_[mr], bf_[nr], acc[mr][nr], 0, 0, 0);                          \
        __builtin_amdgcn_s_setprio(0);                                                \
    } while (0)

    // prologue: stage slices 0,1 (4 loads/wave in flight); slice 0 landed at vmcnt(2)
    STG(0, 0); STG(1, 1);
    asm volatile("s_waitcnt vmcnt(2)" ::: "memory");
    __builtin_amdgcn_s_barrier();

    const int NS = K >> 5;   // 32 slices
    int rs = 0, ss = 2;
    for (int g = 0; g < NS - 2; ++g) {
        BODY(g, rs, ss, true, asm volatile("s_waitcnt vmcnt(2)" ::: "memory"));
        rs = (rs == 2) ? 0 : rs + 1;
        ss = (ss == 2) ? 0 : ss + 1;
    }
    BODY(NS - 2, rs, ss, false, asm volatile("s_waitcnt vmcnt(0)" ::: "memory"));
    rs = (rs == 2) ? 0 : rs + 1;
    BODY(NS - 1, rs, ss, false, (void)0);
#undef BODY
#undef STG

    // epilogue: C/D layout col=lane&15, row=quad*4+reg
    #pragma unroll
    for (int mr = 0; mr < 4; ++mr) {
        #pragma unroll
        for (int nr = 0; nr < 4; ++nr) {
            const int gcol = bn * 256 + wn * 64 + nr * 16 + l16;
            #pragma unroll
            for (int reg = 0; reg < 4; ++reg) {
                const int grow = bm * 256 + wm * 64 + mr * 16 + quad * 4 + reg;
                float v = acc[mr][nr][reg];
                if (BIAS) v += bias[gcol];
                if (BF16_OUT)
                    ((bf16_t*)Cout)[(size_t)grow * N + gcol] = (bf16_t)v;
                else
                    ((float*)Cout)[(size_t)grow * N + gcol] = v;
            }
        }
    }
}

// ---------------------------------------------------------------- block-local attention
// One workgroup per (b, blk, h). q,k: [128][72] LDS; v stored TRANSPOSED with a
// 3-bit chunk-XOR swizzle (write b32-packed pairs of rows -> 2-way banks instead
// of the previous 8-16-way scalar scatter). blockIdx remapped so all 16 heads of
// one (b,blk) -- which share the same 48 KB of qkv rows -- run on the SAME XCD
// (L2 reuse 16x instead of 8x redundant L3 fetches).
__global__ __launch_bounds__(256, 3) void attn_kernel(const bf16_t* __restrict__ qkv,
                                                      bf16_t* __restrict__ attn_out) {
    __shared__ __align__(16) char smem[54272];
    bf16_t* qs = (bf16_t*)smem;                   // [128][72]
    bf16_t* ks = (bf16_t*)(smem + 18432);         // [128][72]
    bf16_t* vT = (bf16_t*)(smem + 36864);         // [64][136]  swizzled: see below
    bf16_t* ps = (bf16_t*)smem;                   // [128][136] overlays qs+ks

    const int tid = threadIdx.x;
    const int lane = tid & 63, wave = tid >> 6;
    const int quad = lane >> 4, l16 = lane & 15;

    // ---- XCD-grouped decode: xcd = gid&7 owns blk ≡ xcd (mod 8); consecutive
    // j within an XCD sweep h fastest -> 16 heads of one (b,blk) co-resident.
    const int gid = blockIdx.x;
    const int xcd = gid & 7;
    const int j = gid >> 3;              // 0..255
    const int h = j & 15;
    const int blkhi = (j >> 4) & 3;
    const int b = j >> 6;
    const int blk = blkhi * 8 + xcd;
    const int row0 = (b * 32 + blk) * 128;   // row base in [16384]
    const int LDQ = 3072;

    // ---- stage q,k (vector, linear)
    for (int t = tid; t < 128 * 8; t += 256) {
        const int r = t >> 3;
        const int c = (t & 7) * 8;           // element offset
        const bf16_t* src = qkv + (size_t)(row0 + r) * LDQ + h * 64;
        *(uint4*)&qs[r * 72 + c] = *(const uint4*)(src + c);
        *(uint4*)&ks[r * 72 + c] = *(const uint4*)(src + 1024 + c);
    }
    // ---- stage v transposed: vT[c][k'] with k' = k ^ ((c>>3 & 7)<<3).
    // Thread packs rows 2r2, 2r2+1 of column c into one b32 -> 2-way banks.
    for (int t = tid; t < 64 * 8; t += 256) {
        const int r2 = t >> 3;               // 0..63 -> rows 2r2, 2r2+1
        const int c0 = (t & 7) * 8;
        const bf16_t* vsrc = qkv + (size_t)(row0 + 2 * r2) * LDQ + h * 64 + 2048 + c0;
        u16x8 v0 = *(const u16x8*)(vsrc);
        u16x8 v1 = *(const u16x8*)(vsrc + LDQ);
        const int X = (t & 7) << 3;          // ((c>>3)&7)<<3, same for c0..c0+7
        #pragma unroll
        for (int jj = 0; jj < 8; jj++) {
            unsigned int pv = (unsigned int)v0[jj] | ((unsigned int)v1[jj] << 16);
            *(unsigned int*)&vT[(c0 + jj) * 136 + ((2 * r2) ^ X)] = pv;
        }
    }
    __syncthreads();

    // ---- S = q k^T / 8 : wave handles rows [wave*32, wave*32+32) x 128 cols
    f32x4 sfrag[2][8];
    for (int mr = 0; mr < 2; mr++)
        for (int nc = 0; nc < 8; nc++)
            sfrag[mr][nc] = (f32x4){0.f, 0.f, 0.f, 0.f};

    #pragma unroll
    for (int ksl = 0; ksl < 2; ksl++) {     // K=64 in two slices of 32
        bf16x8 aq[2], bk[8];
        #pragma unroll
        for (int mr = 0; mr < 2; mr++)
            aq[mr] = *(const bf16x8*)&qs[(wave * 32 + mr * 16 + l16) * 72 + ksl * 32 + quad * 8];
        #pragma unroll
        for (int nc = 0; nc < 8; nc++)
            bk[nc] = *(const bf16x8*)&ks[(nc * 16 + l16) * 72 + ksl * 32 + quad * 8];
        #pragma unroll
        for (int mr = 0; mr < 2; mr++)
            #pragma unroll
            for (int nc = 0; nc < 8; nc++)
                sfrag[mr][nc] = __builtin_amdgcn_mfma_f32_16x16x32_bf16(aq[mr], bk[nc], sfrag[mr][nc], 0, 0, 0);
    }

    // ---- scale + causal mask (C-layout: row=quad*4+reg, col=nc*16+l16)
    #pragma unroll
    for (int mr = 0; mr < 2; mr++) {
        #pragma unroll
        for (int nc = 0; nc < 8; nc++) {
            #pragma unroll
            for (int reg = 0; reg < 4; reg++) {
                const int row = wave * 32 + mr * 16 + quad * 4 + reg;
                const int col = nc * 16 + l16;
                float s = sfrag[mr][nc][reg] * 0.125f;
                if (col > row) s = -INFINITY;
                sfrag[mr][nc][reg] = s;
            }
        }
    }

    // ---- softmax per row
    #pragma unroll
    for (int mr = 0; mr < 2; mr++) {
        #pragma unroll
        for (int reg = 0; reg < 4; reg++) {
            float m = -INFINITY;
            #pragma unroll
            for (int nc = 0; nc < 8; nc++) m = fmaxf(m, sfrag[mr][nc][reg]);
            #pragma unroll
            for (int off = 1; off < 16; off <<= 1) m = fmaxf(m, __shfl_xor(m, off));
            float sum = 0.f;
            #pragma unroll
            for (int nc = 0; nc < 8; nc++) {
                float e = __expf(sfrag[mr][nc][reg] - m);
                sfrag[mr][nc][reg] = e;
                sum += e;
            }
            #pragma unroll
            for (int off = 1; off < 16; off <<= 1) sum += __shfl_xor(sum, off);
            const float inv = 1.0f / (sum + 1e-6f);
            #pragma unroll
            for (int nc = 0; nc < 8; nc++) sfrag[mr][nc][reg] *= inv;
        }
    }

    __syncthreads();   // all waves done reading qs/ks before P overlays them

    // ---- write P (bf16) to LDS [128][136]
    #pragma unroll
    for (int mr = 0; mr < 2; mr++)
        #pragma unroll
        for (int nc = 0; nc < 8; nc++)
            #pragma unroll
            for (int reg = 0; reg < 4; reg++) {
                const int row = wave * 32 + mr * 16 + quad * 4 + reg;
                const int col = nc * 16 + l16;
                ps[row * 136 + col] = (bf16_t)sfrag[mr][nc][reg];
            }
    __syncthreads();

    // ---- O = P @ V : K=128 in 4 slices; V from swizzled vT (b128, aligned)
    f32x4 oacc[2][4];
    for (int mr = 0; mr < 2; mr++)
        for (int nd = 0; nd < 4; nd++)
            oacc[mr][nd] = (f32x4){0.f, 0.f, 0.f, 0.f};

    #pragma unroll
    for (int ksl = 0; ksl < 4; ksl++) {
        bf16x8 ap[2];
        #pragma unroll
        for (int mr = 0; mr < 2; mr++)
            ap[mr] = *(const bf16x8*)&ps[(wave * 32 + mr * 16 + l16) * 136 + ksl * 32 + quad * 8];
        #pragma unroll
        for (int nd = 0; nd < 4; nd++) {
            const int c2 = nd * 16 + l16;
            const int X2 = ((c2 >> 3) & 7) << 3;
            bf16x8 bv = *(const bf16x8*)&vT[c2 * 136 + ((ksl * 32 + quad * 8) ^ X2)];
            #pragma unroll
            for (int mr = 0; mr < 2; mr++)
                oacc[mr][nd] = __builtin_amdgcn_mfma_f32_16x16x32_bf16(ap[mr], bv, oacc[mr][nd], 0, 0, 0);
        }
    }

    // ---- store O bf16 into attn buffer [16384][1024]
    #pragma unroll
    for (int mr = 0; mr < 2; mr++)
        #pragma unroll
        for (int nd = 0; nd < 4; nd++)
            #pragma unroll
            for (int reg = 0; reg < 4; reg++) {
                const int row = row0 + wave * 32 + mr * 16 + quad * 4 + reg;
                const int col = h * 64 + nd * 16 + l16;
                attn_out[(size_t)row * 1024 + col] = (bf16_t)oacc[mr][nd][reg];
            }
}

// ---------------------------------------------------------------- launch
extern "C" void kernel_launch(void* const* d_in, const int* in_sizes, int n_in,
                              void* d_out, int out_size, void* d_ws, size_t ws_size,
                              hipStream_t stream) {
    const float* x     = (const float*)d_in[0];   // [4,4096,1024]
    const float* Wqkv  = (const float*)d_in[1];   // [1024,3072]
    const float* Wproj = (const float*)d_in[2];   // [1024,1024]
    const float* bproj = (const float*)d_in[3];   // [1024]

    const int M = 16384, C = 1024, N1 = 3072;

    // workspace carve (bytes): all 16B aligned
    char* ws = (char*)d_ws;
    bf16_t* xb     = (bf16_t*)(ws);                                   // 32 MB
    bf16_t* wqkvT  = (bf16_t*)(ws + 33554432);                        //  6 MB  [3072][1024]
    bf16_t* wprojT = (bf16_t*)(ws + 39845888);                        //  2 MB  [1024][1024]
    bf16_t* qkvb   = (bf16_t*)(ws + 41943040);                        // 96 MB  [16384][3072]
    bf16_t* attnb  = (bf16_t*)(ws + 142606336);                       // 32 MB  [16384][1024]
    // total 168 MB

    prepass<<<12288, 256, 0, stream>>>(x, xb, Wqkv, wqkvT, Wproj, wprojT);

    // 1D grids, XCD-chunk-swizzled in-kernel: GEMM1 768 = 8*96, GEMM2 256 = 8*32
    gemm256q<true, false><<<(N1 / 256) * (M / 256), 1024, 0, stream>>>(
        xb, wqkvT, (void*)qkvb, nullptr, M, N1, C);

    attn_kernel<<<2048, 256, 0, stream>>>(qkvb, attnb);

    gemm256q<false, true><<<(C / 256) * (M / 256), 1024, 0, stream>>>(
        attnb, wprojT, d_out, bproj, M, C, C);
}